// Round 2
// baseline (434.142 us; speedup 1.0000x reference)
//
#include <hip/hip_runtime.h>

#define N_NODES 50000
#define E_EDGES 800000
#define D 256
#define L 128
#define CAP 64    // max in-degree bucket capacity; Poisson(16) tail => P(overflow) ~ 1e-19
#define SCOL 32   // bf16 columns per XCD slice (64 B); 8 slices cover D=256

typedef __attribute__((ext_vector_type(8))) short bf16x8;
typedef __attribute__((ext_vector_type(4))) float f32x4;

__device__ __forceinline__ float bf2f(unsigned short u) {
    union { unsigned int i; float f; } v; v.i = ((unsigned int)u) << 16; return v.f;
}
__device__ __forceinline__ unsigned short f2bf(float f) {  // round-to-nearest-even
    union { float f; unsigned int i; } v; v.f = f;
    unsigned int r = v.i + 0x7fffu + ((v.i >> 16) & 1u);
    return (unsigned short)(r >> 16);
}
// fp16 pack/unpack for edge weights (always positive, normal range [~0.02, 1])
__device__ __forceinline__ unsigned short f2h(float f) {   // RNE, positive normal
    union { float f; unsigned int i; } v; v.f = f;
    unsigned int r = v.i - 0x38000000u;            // rebias exp 127->15
    r = r + 0xfffu + ((r >> 13) & 1u);             // RNE on 23->10 mantissa cut
    return (unsigned short)(r >> 13);
}
__device__ __forceinline__ float h2f(unsigned int u) {     // positive normal
    union { unsigned int i; float f; } v;
    v.i = ((u & 0x7fffu) << 13) + 0x38000000u;
    return v.f;
}

__global__ __launch_bounds__(256) void zero_i(int* __restrict__ p, int n) {
    int i = blockIdx.x * 256 + threadIdx.x;
    if (i < n) p[i] = 0;
}

// Single-pass bucket build: cursor ends up = in-degree.
__global__ __launch_bounds__(256) void fill_fixed(const int* __restrict__ src,
                                                  const int* __restrict__ dst,
                                                  int* __restrict__ cursor,
                                                  int* __restrict__ bucket) {
    int e = blockIdx.x * 256 + threadIdx.x;
    if (e >= E_EDGES) return;
    int d = dst[e];
    int pos = atomicAdd(&cursor[d], 1);
    if (pos < CAP) bucket[d * CAP + pos] = src[e];
}

__global__ __launch_bounds__(256) void dinv_fin(const int* __restrict__ cursor,
                                                float* __restrict__ dinv) {
    int i = blockIdx.x * 256 + threadIdx.x;
    if (i < N_NODES) dinv[i] = rsqrtf((float)cursor[i] + 1.0f);
}

// In-place: bucket[n][j] = (src & 0xffff) | (fp16(dinv[src]*dinv[n]) << 16).
// src < 65536 since N_NODES = 50000. Slot read+written exactly once.
__global__ __launch_bounds__(256) void pack_bucket(int* __restrict__ bucket,
                                                   const int* __restrict__ cnt_,
                                                   const float* __restrict__ dinv) {
    int node = blockIdx.x * 4 + (threadIdx.x >> 6);
    if (node >= N_NODES) return;
    int lane = threadIdx.x & 63;
    int cnt = cnt_[node]; if (cnt > CAP) cnt = CAP;
    if (lane < cnt) {
        int idx = node * CAP + lane;
        int s = bucket[idx];
        unsigned short wh = f2h(dinv[s] * dinv[node]);
        bucket[idx] = (s & 0xffff) | ((int)wh << 16);
    }
}

// Transpose + split weights into [n][k] bf16 hi/lo. Blocks 0..255: W1 (n=b, k=t).
// Blocks 256..511: Wcat = [Wmu | Wlv] (n=b-256, k=t). Block 256 also fills bcat.
__global__ __launch_bounds__(256) void prep_w(
    const float* __restrict__ W1, const float* __restrict__ Wmu,
    const float* __restrict__ Wlv, const float* __restrict__ bmu,
    const float* __restrict__ blv,
    unsigned short* __restrict__ W1h, unsigned short* __restrict__ W1l,
    unsigned short* __restrict__ Wch, unsigned short* __restrict__ Wcl,
    float* __restrict__ bcat) {
    int b = blockIdx.x, t = threadIdx.x;
    if (b < 256) {
        int n = b, k = t;
        float w = W1[k * 256 + n];
        unsigned short h = f2bf(w);
        W1h[n * 256 + k] = h;
        W1l[n * 256 + k] = f2bf(w - bf2f(h));
    } else {
        int n = b - 256, k = t;
        float w = (n < 128) ? Wmu[k * 128 + n] : Wlv[k * 128 + (n - 128)];
        unsigned short h = f2bf(w);
        Wch[n * 256 + k] = h;
        Wcl[n * 256 + k] = f2bf(w - bf2f(h));
        if (b == 256) bcat[t] = (t < 128) ? bmu[t] : blv[t - 128];
    }
}

// MFMA GEMM: C[M,256] = A_f32[M,256] @ (Bh+Bl)[256,256], fp32-split 3-term.
// A fp32 row-major, split to bf16 hi/lo in-register. Bt* transposed [n][k] bf16.
// Block = 64 rows x 256 cols, 4 waves x 16 rows -> grid 782 (3 blocks/CU).
__global__ __launch_bounds__(256, 3) void gemm_mfma(
    const float* __restrict__ A,
    const unsigned short* __restrict__ Bth, const unsigned short* __restrict__ Btl,
    unsigned short* __restrict__ Hout,
    float* __restrict__ mu, float* __restrict__ lv,
    const float* __restrict__ bias, int M, int mode)
{
    __shared__ unsigned short Bsh[256 * 32];
    __shared__ unsigned short Bsl[256 * 32];
    const int t = threadIdx.x;
    const int lane = t & 63, wave = t >> 6;
    const int row0 = blockIdx.x * 64 + wave * 16;
    const int m_ = lane & 15, q = lane >> 4;
    int rA = row0 + m_; if (rA >= M) rA = M - 1;
    const float* Ap = A + (size_t)rA * 256;
    const int bn = t >> 2;   // B staging: base row 0..63
    const int bc = t & 3;    // chunk 0..3

    f32x4 acc[16];
    const f32x4 zf = {0.f, 0.f, 0.f, 0.f};
#pragma unroll
    for (int nt = 0; nt < 16; ++nt) acc[nt] = zf;

    for (int ks = 0; ks < 8; ++ks) {
        const int k0 = ks * 32;
        bf16x8 gbh[4], gbl[4];
#pragma unroll
        for (int i = 0; i < 4; ++i) {
            int n = bn + i * 64;
            gbh[i] = *(const bf16x8*)(Bth + n * 256 + k0 + bc * 8);
            gbl[i] = *(const bf16x8*)(Btl + n * 256 + k0 + bc * 8);
        }
        float4 av0 = *(const float4*)(Ap + k0 + q * 8);
        float4 av1 = *(const float4*)(Ap + k0 + q * 8 + 4);
        __syncthreads();
#pragma unroll
        for (int i = 0; i < 4; ++i) {
            int n = bn + i * 64;
            int cc = (bc ^ ((n >> 1) & 3)) * 8;
            *(bf16x8*)&Bsh[n * 32 + cc] = gbh[i];
            *(bf16x8*)&Bsl[n * 32 + cc] = gbl[i];
        }
        float af[8] = {av0.x, av0.y, av0.z, av0.w, av1.x, av1.y, av1.z, av1.w};
        bf16x8 ah, al;
#pragma unroll
        for (int j = 0; j < 8; ++j) {
            unsigned short h = f2bf(af[j]);
            ah[j] = (short)h;
            al[j] = (short)f2bf(af[j] - bf2f(h));
        }
        __syncthreads();
#pragma unroll
        for (int nt = 0; nt < 16; ++nt) {
            int n = nt * 16 + m_;
            int cr = (q ^ ((n >> 1) & 3)) * 8;
            bf16x8 bh = *(const bf16x8*)&Bsh[n * 32 + cr];
            bf16x8 bl = *(const bf16x8*)&Bsl[n * 32 + cr];
            acc[nt] = __builtin_amdgcn_mfma_f32_16x16x32_bf16(ah, bh, acc[nt], 0, 0, 0);
            acc[nt] = __builtin_amdgcn_mfma_f32_16x16x32_bf16(ah, bl, acc[nt], 0, 0, 0);
            acc[nt] = __builtin_amdgcn_mfma_f32_16x16x32_bf16(al, bh, acc[nt], 0, 0, 0);
        }
    }
    // epilogue: C/D layout col=lane&15, row=(lane>>4)*4+reg  [m89/m91 verified]
    int rbase = row0 + q * 4;
#pragma unroll
    for (int r = 0; r < 4; ++r) {
        int grow = rbase + r;
        if (grow >= M) continue;
#pragma unroll
        for (int nt = 0; nt < 16; ++nt) {
            int gcol = nt * 16 + m_;
            float v = acc[nt][r];
            if (mode == 0) {
                Hout[(size_t)grow * 256 + gcol] = f2bf(v);
            } else {
                v += bias[gcol];
                if (gcol < 128) mu[(size_t)grow * 128 + gcol] = v;
                else            lv[(size_t)grow * 128 + (gcol - 128)] = v;
            }
        }
    }
}

// XCD-sliced gather: blockIdx%8 = column slice (32 cols = 64 B) -> pinned to one
// XCD by round-robin dispatch; per-XCD working set = 50000 x 64 B = 3.2 MB, fits
// the 4 MB XCD L2 -> L2-miss traffic collapses to cold fill + metadata stream.
// Block = 64 nodes x 1 slice; 4 waves; each 4-lane group owns one node (8 cols/lane).
// Edge stream: one packed 4 B broadcast load per edge (src:16b | w:fp16).
// mode 0: Z = relu(agg + bias) -> bf16. mode 1: Y -> fp32.
__global__ __launch_bounds__(256) void gather_slice(
    const unsigned short* __restrict__ Hs,
    const int* __restrict__ epk, const int* __restrict__ cnt_,
    const float* __restrict__ dinv, const float* __restrict__ bias,
    unsigned short* __restrict__ OutZ, float* __restrict__ OutY, int mode)
{
    const int s = blockIdx.x & 7;           // slice id -> XCD (bid % 8)
    const int g = blockIdx.x >> 3;          // node group
    const int t = threadIdx.x;
    const int node = g * 64 + ((t >> 6) << 4) + ((t & 63) >> 2);
    if (node >= N_NODES) return;
    const int r = t & 3;
    const int col = s * SCOL + r * 8;       // 8 bf16 cols per lane (16 B)
    int cnt = cnt_[node]; if (cnt > CAP) cnt = CAP;
    const float dn = dinv[node];
    const unsigned short* Hp = Hs + col;

    // self-loop term (norm_ii = 1/deg = dn*dn)
    float a[8];
    {
        bf16x8 hv = *(const bf16x8*)(Hp + (size_t)node * D);
        float sl = dn * dn;
#pragma unroll
        for (int p = 0; p < 8; ++p) a[p] = bf2f((unsigned short)hv[p]) * sl;
    }

    const int* ep = epk + node * CAP;
    int j = 0;
    for (; j + 3 < cnt; j += 4) {
        int v0 = ep[j], v1 = ep[j + 1], v2 = ep[j + 2], v3 = ep[j + 3];
        bf16x8 u0 = *(const bf16x8*)(Hp + (size_t)(v0 & 0xffff) * D);
        bf16x8 u1 = *(const bf16x8*)(Hp + (size_t)(v1 & 0xffff) * D);
        bf16x8 u2 = *(const bf16x8*)(Hp + (size_t)(v2 & 0xffff) * D);
        bf16x8 u3 = *(const bf16x8*)(Hp + (size_t)(v3 & 0xffff) * D);
        float w0 = h2f((unsigned int)v0 >> 16), w1 = h2f((unsigned int)v1 >> 16);
        float w2 = h2f((unsigned int)v2 >> 16), w3 = h2f((unsigned int)v3 >> 16);
#pragma unroll
        for (int p = 0; p < 8; ++p) a[p] = fmaf(bf2f((unsigned short)u0[p]), w0, a[p]);
#pragma unroll
        for (int p = 0; p < 8; ++p) a[p] = fmaf(bf2f((unsigned short)u1[p]), w1, a[p]);
#pragma unroll
        for (int p = 0; p < 8; ++p) a[p] = fmaf(bf2f((unsigned short)u2[p]), w2, a[p]);
#pragma unroll
        for (int p = 0; p < 8; ++p) a[p] = fmaf(bf2f((unsigned short)u3[p]), w3, a[p]);
    }
    for (; j < cnt; ++j) {
        int v0 = ep[j];
        bf16x8 u0 = *(const bf16x8*)(Hp + (size_t)(v0 & 0xffff) * D);
        float w0 = h2f((unsigned int)v0 >> 16);
#pragma unroll
        for (int p = 0; p < 8; ++p) a[p] = fmaf(bf2f((unsigned short)u0[p]), w0, a[p]);
    }

    if (mode == 0) {
        float4 b0 = *(const float4*)(bias + col);
        float4 b1 = *(const float4*)(bias + col + 4);
        float bf[8] = {b0.x, b0.y, b0.z, b0.w, b1.x, b1.y, b1.z, b1.w};
        bf16x8 o;
#pragma unroll
        for (int p = 0; p < 8; ++p) o[p] = (short)f2bf(fmaxf(a[p] + bf[p], 0.f));
        *(bf16x8*)(OutZ + (size_t)node * D + col) = o;
    } else {
        float4 o0, o1;
        o0.x = a[0]; o0.y = a[1]; o0.z = a[2]; o0.w = a[3];
        o1.x = a[4]; o1.y = a[5]; o1.z = a[6]; o1.w = a[7];
        float* Yp = OutY + (size_t)node * D + col;
        *(float4*)Yp = o0;
        *(float4*)(Yp + 4) = o1;
    }
}

extern "C" void kernel_launch(void* const* d_in, const int* in_sizes, int n_in,
                              void* d_out, int out_size, void* d_ws, size_t ws_size,
                              hipStream_t stream) {
    const float* x   = (const float*)d_in[0];
    const int*   ei  = (const int*)d_in[1];
    const float* W1  = (const float*)d_in[2];
    const float* b1  = (const float*)d_in[3];
    const float* Wmu = (const float*)d_in[4];
    const float* bmu = (const float*)d_in[5];
    const float* Wlv = (const float*)d_in[6];
    const float* blv = (const float*)d_in[7];
    const int* src = ei;
    const int* dst = ei + E_EDGES;

    const size_t NF = (size_t)N_NODES * D;  // 12.8M
    unsigned short* Hb = (unsigned short*)d_ws;   // [N,256] bf16
    unsigned short* Z  = Hb + NF;                 // [N,256] bf16
    float* Y = (float*)(Z + NF);                  // [N,256] fp32
    unsigned short* W1h = (unsigned short*)(Y + NF);
    unsigned short* W1l = W1h + 65536;
    unsigned short* Wch = W1l + 65536;
    unsigned short* Wcl = Wch + 65536;
    float* bcat = (float*)(Wcl + 65536);
    float* dinv = bcat + 256;
    int* cursor = (int*)(dinv + N_NODES);
    int* bucket = cursor + N_NODES;          // [N*CAP], repacked in place
    float* mu = (float*)d_out;
    float* lv = mu + (size_t)N_NODES * L;

    // graph build: one atomic pass, degrees land in cursor
    zero_i<<<(N_NODES + 255) / 256, 256, 0, stream>>>(cursor, N_NODES);
    fill_fixed<<<(E_EDGES + 255) / 256, 256, 0, stream>>>(src, dst, cursor, bucket);
    dinv_fin<<<(N_NODES + 255) / 256, 256, 0, stream>>>(cursor, dinv);
    pack_bucket<<<(N_NODES + 3) / 4, 256, 0, stream>>>(bucket, cursor, dinv);

    // weight prep
    prep_w<<<512, 256, 0, stream>>>(W1, Wmu, Wlv, bmu, blv, W1h, W1l, Wch, Wcl, bcat);

    const int gemm_blocks = (N_NODES + 63) / 64;        // 782
    const int gat_blocks  = ((N_NODES + 63) / 64) * 8;  // 782 groups x 8 slices
    // layer 1: H = X@W1 (bf16 out)
    gemm_mfma<<<gemm_blocks, 256, 0, stream>>>(x, W1h, W1l, Hb,
                                               nullptr, nullptr, nullptr, N_NODES, 0);
    // Z = relu(P·H + b1)
    gather_slice<<<gat_blocks, 256, 0, stream>>>(Hb, bucket, cursor, dinv, b1,
                                                 Z, nullptr, 0);
    // Y = P·Z (fp32)
    gather_slice<<<gat_blocks, 256, 0, stream>>>(Z, bucket, cursor, dinv, nullptr,
                                                 nullptr, Y, 1);
    // heads: [mu|lv] = Y@[Wmu|Wlv] + [bmu|blv]
    gemm_mfma<<<gemm_blocks, 256, 0, stream>>>(Y, Wch, Wcl, nullptr,
                                               mu, lv, bcat, N_NODES, 1);
}

// Round 3
// 336.206 us; speedup vs baseline: 1.2913x; 1.2913x over previous
//
#include <hip/hip_runtime.h>

#define N_NODES 50000
#define E_EDGES 800000
#define D 256
#define L 128
#define CAP 64   // max in-degree bucket capacity; Poisson(16) tail => P(overflow) ~ 1e-19

typedef __attribute__((ext_vector_type(8))) short bf16x8;
typedef __attribute__((ext_vector_type(4))) float f32x4;

__device__ __forceinline__ float bf2f(unsigned short u) {
    union { unsigned int i; float f; } v; v.i = ((unsigned int)u) << 16; return v.f;
}
__device__ __forceinline__ unsigned short f2bf(float f) {  // round-to-nearest-even
    union { float f; unsigned int i; } v; v.f = f;
    unsigned int r = v.i + 0x7fffu + ((v.i >> 16) & 1u);
    return (unsigned short)(r >> 16);
}

__global__ __launch_bounds__(256) void zero_i(int* __restrict__ p, int n) {
    int i = blockIdx.x * 256 + threadIdx.x;
    if (i < n) p[i] = 0;
}

// Single-pass bucket build: cursor ends up = in-degree.
__global__ __launch_bounds__(256) void fill_fixed(const int* __restrict__ src,
                                                  const int* __restrict__ dst,
                                                  int* __restrict__ cursor,
                                                  int* __restrict__ bucket) {
    int e = blockIdx.x * 256 + threadIdx.x;
    if (e >= E_EDGES) return;
    int d = dst[e];
    int pos = atomicAdd(&cursor[d], 1);
    if (pos < CAP) bucket[d * CAP + pos] = src[e];
}

__global__ __launch_bounds__(256) void dinv_fin(const int* __restrict__ cursor,
                                                float* __restrict__ dinv) {
    int i = blockIdx.x * 256 + threadIdx.x;
    if (i < N_NODES) dinv[i] = rsqrtf((float)cursor[i] + 1.0f);
}

// Transpose + split weights into [n][k] bf16 hi/lo. Blocks 0..255: W1 (n=b, k=t).
// Blocks 256..511: Wcat = [Wmu | Wlv] (n=b-256, k=t). Block 256 also fills bcat.
__global__ __launch_bounds__(256) void prep_w(
    const float* __restrict__ W1, const float* __restrict__ Wmu,
    const float* __restrict__ Wlv, const float* __restrict__ bmu,
    const float* __restrict__ blv,
    unsigned short* __restrict__ W1h, unsigned short* __restrict__ W1l,
    unsigned short* __restrict__ Wch, unsigned short* __restrict__ Wcl,
    float* __restrict__ bcat) {
    int b = blockIdx.x, t = threadIdx.x;
    if (b < 256) {
        int n = b, k = t;
        float w = W1[k * 256 + n];
        unsigned short h = f2bf(w);
        W1h[n * 256 + k] = h;
        W1l[n * 256 + k] = f2bf(w - bf2f(h));
    } else {
        int n = b - 256, k = t;
        float w = (n < 128) ? Wmu[k * 128 + n] : Wlv[k * 128 + (n - 128)];
        unsigned short h = f2bf(w);
        Wch[n * 256 + k] = h;
        Wcl[n * 256 + k] = f2bf(w - bf2f(h));
        if (b == 256) bcat[t] = (t < 128) ? bmu[t] : blv[t - 128];
    }
}

// MFMA GEMM (layer 1): H[M,256] = A_f32[M,256] @ (Bh+Bl)[256,256], fp32-split
// 3-term. A fp32 row-major, split to bf16 hi/lo in-register. Bt* [n][k] bf16.
// Block = 64 rows x 256 cols, 4 waves x 16 rows -> grid 782 (3 blocks/CU).
__global__ __launch_bounds__(256, 3) void gemm_mfma(
    const float* __restrict__ A,
    const unsigned short* __restrict__ Bth, const unsigned short* __restrict__ Btl,
    unsigned short* __restrict__ Hout, int M)
{
    __shared__ unsigned short Bsh[256 * 32];
    __shared__ unsigned short Bsl[256 * 32];
    const int t = threadIdx.x;
    const int lane = t & 63, wave = t >> 6;
    const int row0 = blockIdx.x * 64 + wave * 16;
    const int m_ = lane & 15, q = lane >> 4;
    int rA = row0 + m_; if (rA >= M) rA = M - 1;
    const float* Ap = A + (size_t)rA * 256;
    const int bn = t >> 2;   // B staging: base row 0..63
    const int bc = t & 3;    // chunk 0..3

    f32x4 acc[16];
    const f32x4 zf = {0.f, 0.f, 0.f, 0.f};
#pragma unroll
    for (int nt = 0; nt < 16; ++nt) acc[nt] = zf;

    for (int ks = 0; ks < 8; ++ks) {
        const int k0 = ks * 32;
        bf16x8 gbh[4], gbl[4];
#pragma unroll
        for (int i = 0; i < 4; ++i) {
            int n = bn + i * 64;
            gbh[i] = *(const bf16x8*)(Bth + n * 256 + k0 + bc * 8);
            gbl[i] = *(const bf16x8*)(Btl + n * 256 + k0 + bc * 8);
        }
        float4 av0 = *(const float4*)(Ap + k0 + q * 8);
        float4 av1 = *(const float4*)(Ap + k0 + q * 8 + 4);
        __syncthreads();
#pragma unroll
        for (int i = 0; i < 4; ++i) {
            int n = bn + i * 64;
            int cc = (bc ^ ((n >> 1) & 3)) * 8;
            *(bf16x8*)&Bsh[n * 32 + cc] = gbh[i];
            *(bf16x8*)&Bsl[n * 32 + cc] = gbl[i];
        }
        float af[8] = {av0.x, av0.y, av0.z, av0.w, av1.x, av1.y, av1.z, av1.w};
        bf16x8 ah, al;
#pragma unroll
        for (int j = 0; j < 8; ++j) {
            unsigned short h = f2bf(af[j]);
            ah[j] = (short)h;
            al[j] = (short)f2bf(af[j] - bf2f(h));
        }
        __syncthreads();
#pragma unroll
        for (int nt = 0; nt < 16; ++nt) {
            int n = nt * 16 + m_;
            int cr = (q ^ ((n >> 1) & 3)) * 8;
            bf16x8 bh = *(const bf16x8*)&Bsh[n * 32 + cr];
            bf16x8 bl = *(const bf16x8*)&Bsl[n * 32 + cr];
            acc[nt] = __builtin_amdgcn_mfma_f32_16x16x32_bf16(ah, bh, acc[nt], 0, 0, 0);
            acc[nt] = __builtin_amdgcn_mfma_f32_16x16x32_bf16(ah, bl, acc[nt], 0, 0, 0);
            acc[nt] = __builtin_amdgcn_mfma_f32_16x16x32_bf16(al, bh, acc[nt], 0, 0, 0);
        }
    }
    // epilogue: C/D layout col=lane&15, row=(lane>>4)*4+reg  [m89/m91 verified]
    int rbase = row0 + q * 4;
#pragma unroll
    for (int r = 0; r < 4; ++r) {
        int grow = rbase + r;
        if (grow >= M) continue;
#pragma unroll
        for (int nt = 0; nt < 16; ++nt) {
            int gcol = nt * 16 + m_;
            Hout[(size_t)grow * 256 + gcol] = f2bf(acc[nt][r]);
        }
    }
}

// MFMA GEMM (head): T[M,256] = Z_bf16[M,256] @ (Bh+Bl)[256,256], 2-term (A is
// exact bf16, only B is hi/lo split). Output bf16, bias added later in gather.
__global__ __launch_bounds__(256, 3) void gemm_bf16(
    const unsigned short* __restrict__ A,
    const unsigned short* __restrict__ Bth, const unsigned short* __restrict__ Btl,
    unsigned short* __restrict__ Tout, int M)
{
    __shared__ unsigned short Bsh[256 * 32];
    __shared__ unsigned short Bsl[256 * 32];
    const int t = threadIdx.x;
    const int lane = t & 63, wave = t >> 6;
    const int row0 = blockIdx.x * 64 + wave * 16;
    const int m_ = lane & 15, q = lane >> 4;
    int rA = row0 + m_; if (rA >= M) rA = M - 1;
    const unsigned short* Ap = A + (size_t)rA * 256;
    const int bn = t >> 2;
    const int bc = t & 3;

    f32x4 acc[16];
    const f32x4 zf = {0.f, 0.f, 0.f, 0.f};
#pragma unroll
    for (int nt = 0; nt < 16; ++nt) acc[nt] = zf;

    for (int ks = 0; ks < 8; ++ks) {
        const int k0 = ks * 32;
        bf16x8 gbh[4], gbl[4];
#pragma unroll
        for (int i = 0; i < 4; ++i) {
            int n = bn + i * 64;
            gbh[i] = *(const bf16x8*)(Bth + n * 256 + k0 + bc * 8);
            gbl[i] = *(const bf16x8*)(Btl + n * 256 + k0 + bc * 8);
        }
        bf16x8 ah = *(const bf16x8*)(Ap + k0 + q * 8);
        __syncthreads();
#pragma unroll
        for (int i = 0; i < 4; ++i) {
            int n = bn + i * 64;
            int cc = (bc ^ ((n >> 1) & 3)) * 8;
            *(bf16x8*)&Bsh[n * 32 + cc] = gbh[i];
            *(bf16x8*)&Bsl[n * 32 + cc] = gbl[i];
        }
        __syncthreads();
#pragma unroll
        for (int nt = 0; nt < 16; ++nt) {
            int n = nt * 16 + m_;
            int cr = (q ^ ((n >> 1) & 3)) * 8;
            bf16x8 bh = *(const bf16x8*)&Bsh[n * 32 + cr];
            bf16x8 bl = *(const bf16x8*)&Bsl[n * 32 + cr];
            acc[nt] = __builtin_amdgcn_mfma_f32_16x16x32_bf16(ah, bh, acc[nt], 0, 0, 0);
            acc[nt] = __builtin_amdgcn_mfma_f32_16x16x32_bf16(ah, bl, acc[nt], 0, 0, 0);
        }
    }
    int rbase = row0 + q * 4;
#pragma unroll
    for (int r = 0; r < 4; ++r) {
        int grow = rbase + r;
        if (grow >= M) continue;
#pragma unroll
        for (int nt = 0; nt < 16; ++nt) {
            int gcol = nt * 16 + m_;
            Tout[(size_t)grow * 256 + gcol] = f2bf(acc[nt][r]);
        }
    }
}

// Two dst nodes per wave: each 32-lane half owns one node, 8 bf16 cols/lane
// (16 B loads; one full 512 B row per half-wave memory op). Edge metadata
// preloaded into lane registers, broadcast per-edge via __shfl with the
// half-select bit (lane&32). [r1-verified 63 us / 190 MB fetch — at the
// random-graph per-XCD replication floor.]
// mode 0: Z = relu(agg + b1) -> bf16.
// mode 1: final heads: [mu|lv] = agg(T) + bcat -> fp32, split at col 128.
__global__ __launch_bounds__(256) void gather_pre(
    const unsigned short* __restrict__ Hs,
    const int* __restrict__ bucket, const int* __restrict__ cnt_,
    const float* __restrict__ dinv, const float* __restrict__ bias,
    unsigned short* __restrict__ OutZ,
    float* __restrict__ mu, float* __restrict__ lv, int mode)
{
    const int lane = threadIdx.x & 63;
    const int hl = lane & 31;                 // lane within half-wave
    const int bb = lane & 32;                 // half-select for shfl index
    const int node = blockIdx.x * 8 + (threadIdx.x >> 5);   // 8 nodes/block
    const int col = hl * 8;                   // 8 bf16 columns per lane
    int cnt = cnt_[node]; if (cnt > CAP) cnt = CAP;
    float dn = dinv[node];

    // preload: half-lane j owns edge j (reg0) and edge j+32 (reg1)
    int   s0r = 0, s1r = 0;
    float w0r = 0.f, w1r = 0.f;
    if (hl < cnt)      { s0r = bucket[node * CAP + hl];      w0r = dinv[s0r] * dn; }
    if (hl + 32 < cnt) { s1r = bucket[node * CAP + 32 + hl]; w1r = dinv[s1r] * dn; }

    // start accumulator with the self-loop term (norm_ii = 1/deg = dn*dn)
    float sl = dn * dn;
    bf16x8 hv = *(const bf16x8*)(Hs + (size_t)node * D + col);
    float a[8];
#pragma unroll
    for (int p = 0; p < 8; ++p) a[p] = bf2f((unsigned short)hv[p]) * sl;

    const int cnt0 = cnt < 32 ? cnt : 32;
    int j = 0;
    for (; j + 3 < cnt0; j += 4) {
        int t0 = __shfl(s0r, bb + j,     64), t1 = __shfl(s0r, bb + j + 1, 64);
        int t2 = __shfl(s0r, bb + j + 2, 64), t3 = __shfl(s0r, bb + j + 3, 64);
        float w0 = __shfl(w0r, bb + j,     64), w1 = __shfl(w0r, bb + j + 1, 64);
        float w2 = __shfl(w0r, bb + j + 2, 64), w3 = __shfl(w0r, bb + j + 3, 64);
        bf16x8 u0 = *(const bf16x8*)(Hs + (size_t)t0 * D + col);
        bf16x8 u1 = *(const bf16x8*)(Hs + (size_t)t1 * D + col);
        bf16x8 u2 = *(const bf16x8*)(Hs + (size_t)t2 * D + col);
        bf16x8 u3 = *(const bf16x8*)(Hs + (size_t)t3 * D + col);
#pragma unroll
        for (int p = 0; p < 8; ++p) a[p] = fmaf(bf2f((unsigned short)u0[p]), w0, a[p]);
#pragma unroll
        for (int p = 0; p < 8; ++p) a[p] = fmaf(bf2f((unsigned short)u1[p]), w1, a[p]);
#pragma unroll
        for (int p = 0; p < 8; ++p) a[p] = fmaf(bf2f((unsigned short)u2[p]), w2, a[p]);
#pragma unroll
        for (int p = 0; p < 8; ++p) a[p] = fmaf(bf2f((unsigned short)u3[p]), w3, a[p]);
    }
    for (; j < cnt0; ++j) {
        int   t0 = __shfl(s0r, bb + j, 64);
        float w0 = __shfl(w0r, bb + j, 64);
        bf16x8 u0 = *(const bf16x8*)(Hs + (size_t)t0 * D + col);
#pragma unroll
        for (int p = 0; p < 8; ++p) a[p] = fmaf(bf2f((unsigned short)u0[p]), w0, a[p]);
    }
    if (cnt > 32) {               // Poisson(16) tail: rare
        for (int j2 = 0; j2 < cnt - 32; ++j2) {
            int   t0 = __shfl(s1r, bb + j2, 64);
            float w0 = __shfl(w1r, bb + j2, 64);
            bf16x8 u0 = *(const bf16x8*)(Hs + (size_t)t0 * D + col);
#pragma unroll
            for (int p = 0; p < 8; ++p) a[p] = fmaf(bf2f((unsigned short)u0[p]), w0, a[p]);
        }
    }

    float4 b0 = *(const float4*)(bias + col);
    float4 b1 = *(const float4*)(bias + col + 4);
    float bf[8] = {b0.x, b0.y, b0.z, b0.w, b1.x, b1.y, b1.z, b1.w};
    if (mode == 0) {
        bf16x8 o;
#pragma unroll
        for (int p = 0; p < 8; ++p) o[p] = (short)f2bf(fmaxf(a[p] + bf[p], 0.f));
        *(bf16x8*)(OutZ + (size_t)node * D + col) = o;
    } else {
        float4 o0, o1;
        o0.x = a[0] + bf[0]; o0.y = a[1] + bf[1];
        o0.z = a[2] + bf[2]; o0.w = a[3] + bf[3];
        o1.x = a[4] + bf[4]; o1.y = a[5] + bf[5];
        o1.z = a[6] + bf[6]; o1.w = a[7] + bf[7];
        // col multiple of 8; 8 cols stay within one head (128 % 8 == 0)
        float* Op = (col < 128) ? (mu + (size_t)node * L + col)
                                : (lv + (size_t)node * L + (col - 128));
        *(float4*)Op = o0;
        *(float4*)(Op + 4) = o1;
    }
}

extern "C" void kernel_launch(void* const* d_in, const int* in_sizes, int n_in,
                              void* d_out, int out_size, void* d_ws, size_t ws_size,
                              hipStream_t stream) {
    const float* x   = (const float*)d_in[0];
    const int*   ei  = (const int*)d_in[1];
    const float* W1  = (const float*)d_in[2];
    const float* b1  = (const float*)d_in[3];
    const float* Wmu = (const float*)d_in[4];
    const float* bmu = (const float*)d_in[5];
    const float* Wlv = (const float*)d_in[6];
    const float* blv = (const float*)d_in[7];
    const int* src = ei;
    const int* dst = ei + E_EDGES;

    const size_t NF = (size_t)N_NODES * D;  // 12.8M
    unsigned short* Hb = (unsigned short*)d_ws;   // [N,256] bf16
    unsigned short* Z  = Hb + NF;                 // [N,256] bf16
    unsigned short* T  = Z + NF;                  // [N,256] bf16 = Z @ [Wmu|Wlv]
    unsigned short* W1h = T + NF;
    unsigned short* W1l = W1h + 65536;
    unsigned short* Wch = W1l + 65536;
    unsigned short* Wcl = Wch + 65536;
    float* bcat = (float*)(Wcl + 65536);
    float* dinv = bcat + 256;
    int* cursor = (int*)(dinv + N_NODES);
    int* bucket = cursor + N_NODES;          // [N*CAP]
    float* mu = (float*)d_out;
    float* lv = mu + (size_t)N_NODES * L;

    // graph build: one atomic pass, degrees land in cursor
    zero_i<<<(N_NODES + 255) / 256, 256, 0, stream>>>(cursor, N_NODES);
    fill_fixed<<<(E_EDGES + 255) / 256, 256, 0, stream>>>(src, dst, cursor, bucket);
    dinv_fin<<<(N_NODES + 255) / 256, 256, 0, stream>>>(cursor, dinv);

    // weight prep
    prep_w<<<512, 256, 0, stream>>>(W1, Wmu, Wlv, bmu, blv, W1h, W1l, Wch, Wcl, bcat);

    const int gemm_blocks = (N_NODES + 63) / 64;     // 782
    const int gat_blocks  = N_NODES / 8;             // 6250 (50000 % 8 == 0)
    // layer 1: H = X@W1 (bf16 out)
    gemm_mfma<<<gemm_blocks, 256, 0, stream>>>(x, W1h, W1l, Hb, N_NODES);
    // Z = relu(P·H + b1)
    gather_pre<<<gat_blocks, 256, 0, stream>>>(Hb, bucket, cursor, dinv, b1,
                                               Z, nullptr, nullptr, 0);
    // T = Z @ [Wmu|Wlv]  (bf16; P commutes with right-multiplication)
    gemm_bf16<<<gemm_blocks, 256, 0, stream>>>(Z, Wch, Wcl, T, N_NODES);
    // [mu|lv] = P·T + [bmu|blv]  (fp32, direct to output)
    gather_pre<<<gat_blocks, 256, 0, stream>>>(T, bucket, cursor, dinv, bcat,
                                               nullptr, mu, lv, 1);
}

// Round 4
// 315.215 us; speedup vs baseline: 1.3773x; 1.0666x over previous
//
#include <hip/hip_runtime.h>

#define N_NODES 50000
#define E_EDGES 800000
#define D 256
#define L 128
#define CAP 64   // max in-degree bucket capacity; Poisson(16) tail => P(overflow) ~ 1e-19

typedef __attribute__((ext_vector_type(8))) short bf16x8;
typedef __attribute__((ext_vector_type(4))) float f32x4;

__device__ __forceinline__ float bf2f(unsigned short u) {
    union { unsigned int i; float f; } v; v.i = ((unsigned int)u) << 16; return v.f;
}
__device__ __forceinline__ unsigned short f2bf(float f) {  // round-to-nearest-even
    union { float f; unsigned int i; } v; v.f = f;
    unsigned int r = v.i + 0x7fffu + ((v.i >> 16) & 1u);
    return (unsigned short)(r >> 16);
}

// Single-pass bucket build: cursor ends up = in-degree.
__global__ __launch_bounds__(256) void fill_fixed(const int* __restrict__ src,
                                                  const int* __restrict__ dst,
                                                  int* __restrict__ cursor,
                                                  int* __restrict__ bucket) {
    int e = blockIdx.x * 256 + threadIdx.x;
    if (e >= E_EDGES) return;
    int d = dst[e];
    int pos = atomicAdd(&cursor[d], 1);
    if (pos < CAP) bucket[d * CAP + pos] = src[e];
}

__global__ __launch_bounds__(256) void dinv_fin(const int* __restrict__ cursor,
                                                float* __restrict__ dinv) {
    int i = blockIdx.x * 256 + threadIdx.x;
    if (i < N_NODES) dinv[i] = rsqrtf((float)cursor[i] + 1.0f);
}

// Fused setup: blocks 0..255 transpose/split W1; 256..511 transpose/split
// Wcat=[Wmu|Wlv] (block 256 also fills bcat); 512..707 zero the cursor.
__global__ __launch_bounds__(256) void setup(
    const float* __restrict__ W1, const float* __restrict__ Wmu,
    const float* __restrict__ Wlv, const float* __restrict__ bmu,
    const float* __restrict__ blv,
    unsigned short* __restrict__ W1h, unsigned short* __restrict__ W1l,
    unsigned short* __restrict__ Wch, unsigned short* __restrict__ Wcl,
    float* __restrict__ bcat, int* __restrict__ cursor) {
    int b = blockIdx.x, t = threadIdx.x;
    if (b < 256) {
        int n = b, k = t;
        float w = W1[k * 256 + n];
        unsigned short h = f2bf(w);
        W1h[n * 256 + k] = h;
        W1l[n * 256 + k] = f2bf(w - bf2f(h));
    } else if (b < 512) {
        int n = b - 256, k = t;
        float w = (n < 128) ? Wmu[k * 128 + n] : Wlv[k * 128 + (n - 128)];
        unsigned short h = f2bf(w);
        Wch[n * 256 + k] = h;
        Wcl[n * 256 + k] = f2bf(w - bf2f(h));
        if (b == 256) bcat[t] = (t < 128) ? bmu[t] : blv[t - 128];
    } else {
        int i = (b - 512) * 256 + t;
        if (i < N_NODES) cursor[i] = 0;
    }
}

// MFMA GEMM (layer 1): H[M,256] = X_f32[M,256] @ (Bh+Bl)[256,256], fp32-split
// 3-term. Block = 128 rows x 256 cols, 4 waves 2x2 (each 64 rows x 128 cols).
// Both operands LDS-staged (A split to bf16 hi/lo at stage time), XOR-chunk
// swizzle (measured 0 bank conflicts in the 16-row ancestor).
// Per wave per K-step: 24 ds_read_b128 -> 96 MFMA (3 LDS-cyc/MFMA).
__global__ __launch_bounds__(256, 2) void gemm_mfma(
    const float* __restrict__ A,
    const unsigned short* __restrict__ Bth, const unsigned short* __restrict__ Btl,
    unsigned short* __restrict__ Hout, int M)
{
    __shared__ unsigned short Ash[128 * 32];   // 8 KB
    __shared__ unsigned short Asl[128 * 32];   // 8 KB
    __shared__ unsigned short Bsh[256 * 32];   // 16 KB
    __shared__ unsigned short Bsl[256 * 32];   // 16 KB
    const int t = threadIdx.x;
    const int lane = t & 63, wave = t >> 6;
    const int m_ = lane & 15, q = lane >> 4;
    const int wr = wave >> 1, wc = wave & 1;   // 2x2 wave grid
    const int row0 = blockIdx.x * 128;
    const int sr = t >> 2;                     // staging row 0..63
    const int sc = t & 3;                      // staging chunk 0..3

    f32x4 acc[4][8];
    const f32x4 zf = {0.f, 0.f, 0.f, 0.f};
#pragma unroll
    for (int rs = 0; rs < 4; ++rs)
#pragma unroll
        for (int nt = 0; nt < 8; ++nt) acc[rs][nt] = zf;

    for (int ks = 0; ks < 8; ++ks) {
        const int k0 = ks * 32;
        // global loads: B tile (256n x 32k, hi+lo) and A tile (128 rows fp32)
        bf16x8 gbh[4], gbl[4];
#pragma unroll
        for (int i = 0; i < 4; ++i) {
            int n = sr + i * 64;
            gbh[i] = *(const bf16x8*)(Bth + n * 256 + k0 + sc * 8);
            gbl[i] = *(const bf16x8*)(Btl + n * 256 + k0 + sc * 8);
        }
        float4 ga0[2], ga1[2];
#pragma unroll
        for (int p = 0; p < 2; ++p) {
            int r = row0 + p * 64 + sr; if (r >= M) r = M - 1;
            const float* Xp = A + (size_t)r * 256 + k0 + sc * 8;
            ga0[p] = *(const float4*)Xp;
            ga1[p] = *(const float4*)(Xp + 4);
        }
        __syncthreads();
#pragma unroll
        for (int p = 0; p < 2; ++p) {
            int lr = p * 64 + sr;
            int cc = (sc ^ ((lr >> 1) & 3)) * 8;
            float af[8] = {ga0[p].x, ga0[p].y, ga0[p].z, ga0[p].w,
                           ga1[p].x, ga1[p].y, ga1[p].z, ga1[p].w};
            bf16x8 h, l;
#pragma unroll
            for (int j = 0; j < 8; ++j) {
                unsigned short hh = f2bf(af[j]);
                h[j] = (short)hh;
                l[j] = (short)f2bf(af[j] - bf2f(hh));
            }
            *(bf16x8*)&Ash[lr * 32 + cc] = h;
            *(bf16x8*)&Asl[lr * 32 + cc] = l;
        }
#pragma unroll
        for (int i = 0; i < 4; ++i) {
            int n = sr + i * 64;
            int cc = (sc ^ ((n >> 1) & 3)) * 8;
            *(bf16x8*)&Bsh[n * 32 + cc] = gbh[i];
            *(bf16x8*)&Bsl[n * 32 + cc] = gbl[i];
        }
        __syncthreads();
        // fragment reads + MFMA
        bf16x8 ah[4], al[4];
#pragma unroll
        for (int rs = 0; rs < 4; ++rs) {
            int r = wr * 64 + rs * 16 + m_;
            int cc = (q ^ ((r >> 1) & 3)) * 8;
            ah[rs] = *(const bf16x8*)&Ash[r * 32 + cc];
            al[rs] = *(const bf16x8*)&Asl[r * 32 + cc];
        }
#pragma unroll
        for (int nt = 0; nt < 8; ++nt) {
            int n = wc * 128 + nt * 16 + m_;
            int cr = (q ^ ((n >> 1) & 3)) * 8;
            bf16x8 bh = *(const bf16x8*)&Bsh[n * 32 + cr];
            bf16x8 bl = *(const bf16x8*)&Bsl[n * 32 + cr];
#pragma unroll
            for (int rs = 0; rs < 4; ++rs) {
                acc[rs][nt] = __builtin_amdgcn_mfma_f32_16x16x32_bf16(ah[rs], bh, acc[rs][nt], 0, 0, 0);
                acc[rs][nt] = __builtin_amdgcn_mfma_f32_16x16x32_bf16(ah[rs], bl, acc[rs][nt], 0, 0, 0);
                acc[rs][nt] = __builtin_amdgcn_mfma_f32_16x16x32_bf16(al[rs], bh, acc[rs][nt], 0, 0, 0);
            }
        }
    }
    // epilogue: C/D layout col=lane&15, row=(lane>>4)*4+reg  [m89/m91 verified]
#pragma unroll
    for (int rs = 0; rs < 4; ++rs) {
        int rbase = row0 + wr * 64 + rs * 16 + q * 4;
#pragma unroll
        for (int rr = 0; rr < 4; ++rr) {
            int grow = rbase + rr;
            if (grow >= M) continue;
#pragma unroll
            for (int nt = 0; nt < 8; ++nt) {
                int gcol = wc * 128 + nt * 16 + m_;
                Hout[(size_t)grow * 256 + gcol] = f2bf(acc[rs][nt][rr]);
            }
        }
    }
}

// MFMA GEMM (head): T[M,256] = Z_bf16[M,256] @ (Bh+Bl)[256,256], 2-term (A is
// exact bf16). Same 128x256 block / 2x2 wave structure. Output bf16.
__global__ __launch_bounds__(256, 2) void gemm_bf16(
    const unsigned short* __restrict__ A,
    const unsigned short* __restrict__ Bth, const unsigned short* __restrict__ Btl,
    unsigned short* __restrict__ Tout, int M)
{
    __shared__ unsigned short Ash[128 * 32];   // 8 KB
    __shared__ unsigned short Bsh[256 * 32];   // 16 KB
    __shared__ unsigned short Bsl[256 * 32];   // 16 KB
    const int t = threadIdx.x;
    const int lane = t & 63, wave = t >> 6;
    const int m_ = lane & 15, q = lane >> 4;
    const int wr = wave >> 1, wc = wave & 1;
    const int row0 = blockIdx.x * 128;
    const int sr = t >> 2;
    const int sc = t & 3;

    f32x4 acc[4][8];
    const f32x4 zf = {0.f, 0.f, 0.f, 0.f};
#pragma unroll
    for (int rs = 0; rs < 4; ++rs)
#pragma unroll
        for (int nt = 0; nt < 8; ++nt) acc[rs][nt] = zf;

    for (int ks = 0; ks < 8; ++ks) {
        const int k0 = ks * 32;
        bf16x8 gbh[4], gbl[4];
#pragma unroll
        for (int i = 0; i < 4; ++i) {
            int n = sr + i * 64;
            gbh[i] = *(const bf16x8*)(Bth + n * 256 + k0 + sc * 8);
            gbl[i] = *(const bf16x8*)(Btl + n * 256 + k0 + sc * 8);
        }
        bf16x8 gav[2];
#pragma unroll
        for (int p = 0; p < 2; ++p) {
            int r = row0 + p * 64 + sr; if (r >= M) r = M - 1;
            gav[p] = *(const bf16x8*)(A + (size_t)r * 256 + k0 + sc * 8);
        }
        __syncthreads();
#pragma unroll
        for (int p = 0; p < 2; ++p) {
            int lr = p * 64 + sr;
            int cc = (sc ^ ((lr >> 1) & 3)) * 8;
            *(bf16x8*)&Ash[lr * 32 + cc] = gav[p];
        }
#pragma unroll
        for (int i = 0; i < 4; ++i) {
            int n = sr + i * 64;
            int cc = (sc ^ ((n >> 1) & 3)) * 8;
            *(bf16x8*)&Bsh[n * 32 + cc] = gbh[i];
            *(bf16x8*)&Bsl[n * 32 + cc] = gbl[i];
        }
        __syncthreads();
        bf16x8 ah[4];
#pragma unroll
        for (int rs = 0; rs < 4; ++rs) {
            int r = wr * 64 + rs * 16 + m_;
            int cc = (q ^ ((r >> 1) & 3)) * 8;
            ah[rs] = *(const bf16x8*)&Ash[r * 32 + cc];
        }
#pragma unroll
        for (int nt = 0; nt < 8; ++nt) {
            int n = wc * 128 + nt * 16 + m_;
            int cr = (q ^ ((n >> 1) & 3)) * 8;
            bf16x8 bh = *(const bf16x8*)&Bsh[n * 32 + cr];
            bf16x8 bl = *(const bf16x8*)&Bsl[n * 32 + cr];
#pragma unroll
            for (int rs = 0; rs < 4; ++rs) {
                acc[rs][nt] = __builtin_amdgcn_mfma_f32_16x16x32_bf16(ah[rs], bh, acc[rs][nt], 0, 0, 0);
                acc[rs][nt] = __builtin_amdgcn_mfma_f32_16x16x32_bf16(ah[rs], bl, acc[rs][nt], 0, 0, 0);
            }
        }
    }
#pragma unroll
    for (int rs = 0; rs < 4; ++rs) {
        int rbase = row0 + wr * 64 + rs * 16 + q * 4;
#pragma unroll
        for (int rr = 0; rr < 4; ++rr) {
            int grow = rbase + rr;
            if (grow >= M) continue;
#pragma unroll
            for (int nt = 0; nt < 8; ++nt) {
                int gcol = wc * 128 + nt * 16 + m_;
                Tout[(size_t)grow * 256 + gcol] = f2bf(acc[rs][nt][rr]);
            }
        }
    }
}

// Two dst nodes per wave: each 32-lane half owns one node, 8 bf16 cols/lane
// (16 B loads; one full 512 B row per half-wave memory op). Edge metadata
// preloaded into lane registers, broadcast per-edge via __shfl with the
// half-select bit (lane&32). [r1/r3-verified 63 us / 190 MB fetch — at the
// random-graph per-XCD replication floor (~3 TB/s miss path).]
// mode 0: Z = relu(agg + b1) -> bf16.
// mode 1: final heads: [mu|lv] = agg(T) + bcat -> fp32, split at col 128.
__global__ __launch_bounds__(256) void gather_pre(
    const unsigned short* __restrict__ Hs,
    const int* __restrict__ bucket, const int* __restrict__ cnt_,
    const float* __restrict__ dinv, const float* __restrict__ bias,
    unsigned short* __restrict__ OutZ,
    float* __restrict__ mu, float* __restrict__ lv, int mode)
{
    const int lane = threadIdx.x & 63;
    const int hl = lane & 31;                 // lane within half-wave
    const int bb = lane & 32;                 // half-select for shfl index
    const int node = blockIdx.x * 8 + (threadIdx.x >> 5);   // 8 nodes/block
    const int col = hl * 8;                   // 8 bf16 columns per lane
    int cnt = cnt_[node]; if (cnt > CAP) cnt = CAP;
    float dn = dinv[node];

    // preload: half-lane j owns edge j (reg0) and edge j+32 (reg1)
    int   s0r = 0, s1r = 0;
    float w0r = 0.f, w1r = 0.f;
    if (hl < cnt)      { s0r = bucket[node * CAP + hl];      w0r = dinv[s0r] * dn; }
    if (hl + 32 < cnt) { s1r = bucket[node * CAP + 32 + hl]; w1r = dinv[s1r] * dn; }

    // start accumulator with the self-loop term (norm_ii = 1/deg = dn*dn)
    float sl = dn * dn;
    bf16x8 hv = *(const bf16x8*)(Hs + (size_t)node * D + col);
    float a[8];
#pragma unroll
    for (int p = 0; p < 8; ++p) a[p] = bf2f((unsigned short)hv[p]) * sl;

    const int cnt0 = cnt < 32 ? cnt : 32;
    int j = 0;
    for (; j + 3 < cnt0; j += 4) {
        int t0 = __shfl(s0r, bb + j,     64), t1 = __shfl(s0r, bb + j + 1, 64);
        int t2 = __shfl(s0r, bb + j + 2, 64), t3 = __shfl(s0r, bb + j + 3, 64);
        float w0 = __shfl(w0r, bb + j,     64), w1 = __shfl(w0r, bb + j + 1, 64);
        float w2 = __shfl(w0r, bb + j + 2, 64), w3 = __shfl(w0r, bb + j + 3, 64);
        bf16x8 u0 = *(const bf16x8*)(Hs + (size_t)t0 * D + col);
        bf16x8 u1 = *(const bf16x8*)(Hs + (size_t)t1 * D + col);
        bf16x8 u2 = *(const bf16x8*)(Hs + (size_t)t2 * D + col);
        bf16x8 u3 = *(const bf16x8*)(Hs + (size_t)t3 * D + col);
#pragma unroll
        for (int p = 0; p < 8; ++p) a[p] = fmaf(bf2f((unsigned short)u0[p]), w0, a[p]);
#pragma unroll
        for (int p = 0; p < 8; ++p) a[p] = fmaf(bf2f((unsigned short)u1[p]), w1, a[p]);
#pragma unroll
        for (int p = 0; p < 8; ++p) a[p] = fmaf(bf2f((unsigned short)u2[p]), w2, a[p]);
#pragma unroll
        for (int p = 0; p < 8; ++p) a[p] = fmaf(bf2f((unsigned short)u3[p]), w3, a[p]);
    }
    for (; j < cnt0; ++j) {
        int   t0 = __shfl(s0r, bb + j, 64);
        float w0 = __shfl(w0r, bb + j, 64);
        bf16x8 u0 = *(const bf16x8*)(Hs + (size_t)t0 * D + col);
#pragma unroll
        for (int p = 0; p < 8; ++p) a[p] = fmaf(bf2f((unsigned short)u0[p]), w0, a[p]);
    }
    if (cnt > 32) {               // Poisson(16) tail: rare
        for (int j2 = 0; j2 < cnt - 32; ++j2) {
            int   t0 = __shfl(s1r, bb + j2, 64);
            float w0 = __shfl(w1r, bb + j2, 64);
            bf16x8 u0 = *(const bf16x8*)(Hs + (size_t)t0 * D + col);
#pragma unroll
            for (int p = 0; p < 8; ++p) a[p] = fmaf(bf2f((unsigned short)u0[p]), w0, a[p]);
        }
    }

    float4 b0 = *(const float4*)(bias + col);
    float4 b1 = *(const float4*)(bias + col + 4);
    float bf[8] = {b0.x, b0.y, b0.z, b0.w, b1.x, b1.y, b1.z, b1.w};
    if (mode == 0) {
        bf16x8 o;
#pragma unroll
        for (int p = 0; p < 8; ++p) o[p] = (short)f2bf(fmaxf(a[p] + bf[p], 0.f));
        *(bf16x8*)(OutZ + (size_t)node * D + col) = o;
    } else {
        float4 o0, o1;
        o0.x = a[0] + bf[0]; o0.y = a[1] + bf[1];
        o0.z = a[2] + bf[2]; o0.w = a[3] + bf[3];
        o1.x = a[4] + bf[4]; o1.y = a[5] + bf[5];
        o1.z = a[6] + bf[6]; o1.w = a[7] + bf[7];
        // col multiple of 8; 8 cols stay within one head (128 % 8 == 0)
        float* Op = (col < 128) ? (mu + (size_t)node * L + col)
                                : (lv + (size_t)node * L + (col - 128));
        *(float4*)Op = o0;
        *(float4*)(Op + 4) = o1;
    }
}

extern "C" void kernel_launch(void* const* d_in, const int* in_sizes, int n_in,
                              void* d_out, int out_size, void* d_ws, size_t ws_size,
                              hipStream_t stream) {
    const float* x   = (const float*)d_in[0];
    const int*   ei  = (const int*)d_in[1];
    const float* W1  = (const float*)d_in[2];
    const float* b1  = (const float*)d_in[3];
    const float* Wmu = (const float*)d_in[4];
    const float* bmu = (const float*)d_in[5];
    const float* Wlv = (const float*)d_in[6];
    const float* blv = (const float*)d_in[7];
    const int* src = ei;
    const int* dst = ei + E_EDGES;

    const size_t NF = (size_t)N_NODES * D;  // 12.8M
    unsigned short* Hb = (unsigned short*)d_ws;   // [N,256] bf16
    unsigned short* Z  = Hb + NF;                 // [N,256] bf16
    unsigned short* T  = Z + NF;                  // [N,256] bf16 = Z @ [Wmu|Wlv]
    unsigned short* W1h = T + NF;
    unsigned short* W1l = W1h + 65536;
    unsigned short* Wch = W1l + 65536;
    unsigned short* Wcl = Wch + 65536;
    float* bcat = (float*)(Wcl + 65536);
    float* dinv = bcat + 256;
    int* cursor = (int*)(dinv + N_NODES);
    int* bucket = cursor + N_NODES;          // [N*CAP]
    float* mu = (float*)d_out;
    float* lv = mu + (size_t)N_NODES * L;

    // setup: weight transpose/split + cursor zeroing in one launch
    setup<<<512 + (N_NODES + 255) / 256, 256, 0, stream>>>(
        W1, Wmu, Wlv, bmu, blv, W1h, W1l, Wch, Wcl, bcat, cursor);
    // graph build: one atomic pass, degrees land in cursor
    fill_fixed<<<(E_EDGES + 255) / 256, 256, 0, stream>>>(src, dst, cursor, bucket);
    dinv_fin<<<(N_NODES + 255) / 256, 256, 0, stream>>>(cursor, dinv);

    const int gemm_blocks = (N_NODES + 127) / 128;   // 391
    const int gat_blocks  = N_NODES / 8;             // 6250 (50000 % 8 == 0)
    // layer 1: H = X@W1 (bf16 out)
    gemm_mfma<<<gemm_blocks, 256, 0, stream>>>(x, W1h, W1l, Hb, N_NODES);
    // Z = relu(P·H + b1)
    gather_pre<<<gat_blocks, 256, 0, stream>>>(Hb, bucket, cursor, dinv, b1,
                                               Z, nullptr, nullptr, 0);
    // T = Z @ [Wmu|Wlv]  (bf16; P commutes with right-multiplication)
    gemm_bf16<<<gemm_blocks, 256, 0, stream>>>(Z, Wch, Wcl, T, N_NODES);
    // [mu|lv] = P·T + [bmu|blv]  (fp32, direct to output)
    gather_pre<<<gat_blocks, 256, 0, stream>>>(T, bucket, cursor, dinv, bcat,
                                               nullptr, mu, lv, 1);
}